// Round 4
// baseline (104.198 us; speedup 1.0000x reference)
//
#include <hip/hip_runtime.h>

// Problem geometry (fixed by reference): B*T = 128 batches, N = 65536 rows, 3 coords.
constexpr int N_ROWS  = 65536;
constexpr int NBATCH  = 128;
constexpr int THREADS = 256;
constexpr int BPB     = 16;                               // blocks per batch
constexpr int ROWS_PER_BLOCK = N_ROWS / BPB;              // 4096
constexpr int NPASS = ROWS_PER_BLOCK / (THREADS * 4);     // 4
constexpr int GS    = THREADS * 3;                        // float4 stride per pass

// Key identity: out[b,c] = sqrt(min_d ( ra[b,c] - 2*mul[b,c,d] + rb[b,d] )).
// One pass computing 15 sums per batch reproduces the reference exactly.

// 4 rows = 3 float4 (48 B), row-aligned.
struct G4 { float4 a, b, c; };

__device__ __forceinline__ void accum_g(const G4& P, const G4& T, float acc[15]) {
    const float pf[12] = {P.a.x,P.a.y,P.a.z,P.a.w, P.b.x,P.b.y,P.b.z,P.b.w,
                          P.c.x,P.c.y,P.c.z,P.c.w};
    const float tf[12] = {T.a.x,T.a.y,T.a.z,T.a.w, T.b.x,T.b.y,T.b.z,T.b.w,
                          T.c.x,T.c.y,T.c.z,T.c.w};
    #pragma unroll
    for (int r = 0; r < 4; ++r) {
        const float p0 = pf[r*3+0], p1 = pf[r*3+1], p2 = pf[r*3+2];
        const float t0 = tf[r*3+0], t1 = tf[r*3+1], t2 = tf[r*3+2];
        acc[0]  = fmaf(p0,p0,acc[0]);  acc[1]  = fmaf(p1,p1,acc[1]);  acc[2]  = fmaf(p2,p2,acc[2]);
        acc[3]  = fmaf(t0,t0,acc[3]);  acc[4]  = fmaf(t1,t1,acc[4]);  acc[5]  = fmaf(t2,t2,acc[5]);
        acc[6]  = fmaf(p0,t0,acc[6]);  acc[7]  = fmaf(p0,t1,acc[7]);  acc[8]  = fmaf(p0,t2,acc[8]);
        acc[9]  = fmaf(p1,t0,acc[9]);  acc[10] = fmaf(p1,t1,acc[10]); acc[11] = fmaf(p1,t2,acc[11]);
        acc[12] = fmaf(p2,t0,acc[12]); acc[13] = fmaf(p2,t1,acc[13]); acc[14] = fmaf(p2,t2,acc[14]);
    }
}

// 2-deep software pipeline: prefetch pass p+1's 6 float4 while accumulating
// pass p. Peak live ~= 15 acc + 24 cur + 24 next + addr ~= 70 VGPR.
// __launch_bounds__(256, 6): cap ~84 regs — big enough that the allocator
// can't squeeze to 32 (R0: serialized loads) and small enough that it can't
// balloon/spill (R2/R3: WRITE_SIZE 80MB/19MB of scratch at monolithic 24-load
// clusters). sched_barrier(0) pins the prefetch above the FMAs so the
// compiler emits the counted-vmcnt pipeline (6 loads in flight across the
// compute phase).
__global__ __launch_bounds__(THREADS, 6)
void nn_partial16(const float* __restrict__ pred,
                  const float* __restrict__ targ,
                  float* __restrict__ partial) {
    const int bid   = blockIdx.x;
    const int batch = bid >> 4;          // bpb == 16
    const int chunk = bid & 15;
    const long base = (long)batch * (N_ROWS * 3) + (long)chunk * ROWS_PER_BLOCK * 3;
    const int  tid  = threadIdx.x;

    const float4* __restrict__ pA =
        reinterpret_cast<const float4*>(pred + base) + (long)tid * 3;
    const float4* __restrict__ tA =
        reinterpret_cast<const float4*>(targ + base) + (long)tid * 3;

    float acc[15];
    #pragma unroll
    for (int i = 0; i < 15; ++i) acc[i] = 0.f;

    // Prologue: load pass 0.
    G4 P{pA[0], pA[1], pA[2]};
    G4 T{tA[0], tA[1], tA[2]};

    #pragma unroll
    for (int pass = 0; pass < NPASS; ++pass) {
        G4 Pn, Tn;
        if (pass + 1 < NPASS) {
            const float4* pn = pA + (long)(pass + 1) * GS;
            const float4* tn = tA + (long)(pass + 1) * GS;
            Pn.a = pn[0]; Pn.b = pn[1]; Pn.c = pn[2];
            Tn.a = tn[0]; Tn.b = tn[1]; Tn.c = tn[2];
            __builtin_amdgcn_sched_barrier(0);  // prefetch stays above FMAs
        }
        accum_g(P, T, acc);
        if (pass + 1 < NPASS) { P = Pn; T = Tn; }
    }

    // Wave (64-lane) butterfly reduce for each of the 15 accumulators.
    #pragma unroll
    for (int off = 32; off > 0; off >>= 1) {
        #pragma unroll
        for (int i = 0; i < 15; ++i)
            acc[i] += __shfl_down(acc[i], off, 64);
    }

    __shared__ float wsum[4][15];
    const int wave = tid >> 6;
    const int lane = tid & 63;
    if (lane == 0) {
        #pragma unroll
        for (int i = 0; i < 15; ++i) wsum[wave][i] = acc[i];
    }
    __syncthreads();
    if (tid < 15) {
        partial[(long)bid * 15 + tid] =
            wsum[0][tid] + wsum[1][tid] + wsum[2][tid] + wsum[3][tid];
    }
}

// Generic fallback (only used if ws_size forces a non-standard bpb).
__global__ __launch_bounds__(THREADS)
void nn_partial_gen(const float* __restrict__ pred,
                    const float* __restrict__ targ,
                    float* __restrict__ partial,
                    int bpb, int npass) {
    const int bid   = blockIdx.x;
    const int batch = bid / bpb;
    const int chunk = bid - batch * bpb;
    const int rows_per_block = N_ROWS / bpb;
    const long base = (long)batch * (N_ROWS * 3) + (long)chunk * rows_per_block * 3;
    const float4* __restrict__ p4 = reinterpret_cast<const float4*>(pred + base);
    const float4* __restrict__ t4 = reinterpret_cast<const float4*>(targ + base);

    float acc[15];
    #pragma unroll
    for (int i = 0; i < 15; ++i) acc[i] = 0.f;

    const int tid = threadIdx.x;
    for (int pass = 0; pass < npass; ++pass) {
        const int v = (pass * THREADS + tid) * 3;
        G4 P{p4[v+0], p4[v+1], p4[v+2]};
        G4 T{t4[v+0], t4[v+1], t4[v+2]};
        accum_g(P, T, acc);
    }

    #pragma unroll
    for (int off = 32; off > 0; off >>= 1) {
        #pragma unroll
        for (int i = 0; i < 15; ++i)
            acc[i] += __shfl_down(acc[i], off, 64);
    }

    __shared__ float wsum[4][15];
    const int wave = tid >> 6;
    const int lane = tid & 63;
    if (lane == 0) {
        #pragma unroll
        for (int i = 0; i < 15; ++i) wsum[wave][i] = acc[i];
    }
    __syncthreads();
    if (tid < 15) {
        partial[(long)bid * 15 + tid] =
            wsum[0][tid] + wsum[1][tid] + wsum[2][tid] + wsum[3][tid];
    }
}

// One block per batch, 64 lanes: lane k < bpb owns one partial vector,
// shfl tree sums across the (<=16) chunks, lane 0 finalizes.
__global__ void nn_final_kernel(const float* __restrict__ partial,
                                float* __restrict__ out, int bpb) {
    const int b    = blockIdx.x;
    const int lane = threadIdx.x;
    float s[15];
    if (lane < bpb) {
        const float* pp = partial + (long)(b * bpb + lane) * 15;
        #pragma unroll
        for (int i = 0; i < 15; ++i) s[i] = pp[i];
    } else {
        #pragma unroll
        for (int i = 0; i < 15; ++i) s[i] = 0.f;
    }
    #pragma unroll
    for (int off = 8; off > 0; off >>= 1) {
        #pragma unroll
        for (int i = 0; i < 15; ++i)
            s[i] += __shfl_down(s[i], off, 64);
    }
    if (lane == 0) {
        #pragma unroll
        for (int c = 0; c < 3; ++c) {
            float m = 3.0e38f;
            #pragma unroll
            for (int d = 0; d < 3; ++d) {
                float dist = s[c] - 2.0f * s[6 + c * 3 + d] + s[3 + d];
                m = fminf(m, dist);
            }
            out[b * 3 + c] = sqrtf(fmaxf(m, 0.f));
        }
    }
}

extern "C" void kernel_launch(void* const* d_in, const int* in_sizes, int n_in,
                              void* d_out, int out_size, void* d_ws, size_t ws_size,
                              hipStream_t stream) {
    const float* pred = (const float*)d_in[0];
    const float* targ = (const float*)d_in[1];
    float* out     = (float*)d_out;
    float* partial = (float*)d_ws;

    int bpb = BPB;
    while (bpb > 1 && (size_t)(NBATCH * bpb) * 15 * sizeof(float) > ws_size) bpb >>= 1;

    if (bpb == BPB) {
        nn_partial16<<<NBATCH * BPB, THREADS, 0, stream>>>(pred, targ, partial);
    } else {
        const int npass = (N_ROWS / bpb) / (THREADS * 4);
        nn_partial_gen<<<NBATCH * bpb, THREADS, 0, stream>>>(pred, targ, partial, bpb, npass);
    }
    nn_final_kernel<<<NBATCH, 64, 0, stream>>>(partial, out, bpb);
}